// Round 3
// baseline (604.822 us; speedup 1.0000x reference)
//
#include <hip/hip_runtime.h>
#include <stdint.h>

typedef unsigned short ushort_t;
typedef __bf16 bf16x8 __attribute__((ext_vector_type(8)));
typedef float f32x4 __attribute__((ext_vector_type(4)));

#define T_TOK 8192
#define HDIM  1024
#define EXP   8
#define FDIM  2048
#define CAP   1280

// fp32 -> bf16 round-to-nearest-even
__device__ __forceinline__ unsigned short f2b(float f) {
  unsigned u = __float_as_uint(f);
  u = (u + 0x7fffu + ((u >> 16) & 1u)) >> 16;
  return (unsigned short)u;
}
__device__ __forceinline__ unsigned pk2(unsigned short lo, unsigned short hi) {
  return (unsigned)lo | ((unsigned)hi << 16);
}
// order-preserving fp32 -> u32 map (monotone increasing)
__device__ __forceinline__ unsigned map_u(float f) {
  unsigned u = __float_as_uint(f);
  return (u & 0x80000000u) ? ~u : (u | 0x80000000u);
}
__device__ __forceinline__ float unmap_f(unsigned m) {
  unsigned u = (m & 0x80000000u) ? (m ^ 0x80000000u) : ~m;
  return __uint_as_float(u);
}
// async global->LDS, 16B/lane; LDS dest = wave-uniform base + lane*16
__device__ __forceinline__ void gl_lds16(const void* g, void* l) {
  __builtin_amdgcn_global_load_lds((__attribute__((address_space(1))) void*)g,
                                   (__attribute__((address_space(3))) void*)l,
                                   16, 0, 0);
}

// ------------------------------------------- gating GEMV + x->bf16 cast (fused)
// one wave per token; writes logitsT[e][t] (coalesced for select/emit) and xb.
__global__ void __launch_bounds__(256) gate_cast_k(
    const float* __restrict__ x, const float* __restrict__ gw,
    float* __restrict__ logitsT, ushort_t* __restrict__ xb)
{
  int wave = threadIdx.x >> 6, lane = threadIdx.x & 63;
  int t = blockIdx.x * 4 + wave;
  const float* xr = x + (size_t)t * HDIM;
  ushort_t* xbr = xb + (size_t)t * HDIM;
  float acc[8];
#pragma unroll
  for (int i = 0; i < 8; ++i) acc[i] = 0.f;
#pragma unroll
  for (int i = 0; i < 16; ++i) {
    int h = i * 64 + lane;
    float xv = xr[h];
    xbr[h] = f2b(xv);
    const float4* g4 = (const float4*)(gw + (size_t)h * EXP);
    float4 lo = g4[0], hi = g4[1];
    acc[0] += xv * lo.x; acc[1] += xv * lo.y; acc[2] += xv * lo.z; acc[3] += xv * lo.w;
    acc[4] += xv * hi.x; acc[5] += xv * hi.y; acc[6] += xv * hi.z; acc[7] += xv * hi.w;
  }
#pragma unroll
  for (int off = 32; off > 0; off >>= 1) {
#pragma unroll
    for (int i = 0; i < 8; ++i) acc[i] += __shfl_xor(acc[i], off, 64);
  }
  if (lane == 0) {
#pragma unroll
    for (int i = 0; i < 8; ++i) logitsT[(size_t)i * T_TOK + t] = acc[i];
  }
}

// ------------------------------- radix-select: exact CAP-th largest per expert
// one block per expert; values register-cached (32/thread); 4 x 8-bit narrowing.
__global__ void __launch_bounds__(256) select_k(
    const float* __restrict__ logitsT,
    unsigned* __restrict__ thr, int* __restrict__ need, unsigned* __restrict__ umax)
{
  __shared__ int hist[256];
  __shared__ unsigned s_pref, s_max;
  __shared__ int s_rem;
  int e = blockIdx.x, tid = threadIdx.x;
  const float* base = logitsT + (size_t)e * T_TOK;

  unsigned m[32];
#pragma unroll
  for (int i = 0; i < 32; ++i) m[i] = map_u(base[tid + i * 256]);

  if (tid == 0) { s_pref = 0; s_rem = CAP; s_max = 0; }
  __syncthreads();

  for (int r = 0; r < 4; ++r) {
    hist[tid] = 0;
    __syncthreads();
    unsigned pref = s_pref;
    int shift = 24 - 8 * r, hi = 32 - 8 * r;
#pragma unroll
    for (int i = 0; i < 32; ++i) {
      unsigned u = m[i];
      if (r == 0) {
        atomicMax(&s_max, u);
        atomicAdd(&hist[u >> 24], 1);
      } else if ((u >> hi) == (pref >> hi)) {
        atomicAdd(&hist[(u >> shift) & 255], 1);
      }
    }
    __syncthreads();
    if (tid == 0) {
      int rem = s_rem, acc = 0, b;
      for (b = 255; b >= 0; --b) {
        int c = hist[b];
        if (acc + c >= rem) break;
        acc += c;
      }
      s_pref = pref | ((unsigned)b << shift);
      s_rem = rem - acc;
    }
    __syncthreads();
  }
  if (tid == 0) {
    thr[e] = s_pref;       // exact CAP-th largest (mapped)
    need[e] = s_rem;       // how many == thr to admit (>=1)
    umax[e] = s_max;
  }
}

// ------------------------- emit: threshold test + slot assign + exp / expsum
// wave-ballot aggregation: 1 atomicAdd per wave per expert on the slot counter.
__global__ void __launch_bounds__(256) emit_k(
    const float* __restrict__ logitsT,
    const unsigned* __restrict__ thr, const int* __restrict__ need,
    const unsigned* __restrict__ umax,
    int* __restrict__ idxo, float* __restrict__ exo,
    int* __restrict__ cnt, int* __restrict__ tie, float* __restrict__ expsum)
{
  int t = blockIdx.x * 256 + threadIdx.x;
  int lane = threadIdx.x & 63;
#pragma unroll
  for (int e = 0; e < EXP; ++e) {
    float f = logitsT[(size_t)e * T_TOK + t];
    unsigned u = map_u(f);
    unsigned te = thr[e];
    float fm = unmap_f(umax[e]);
    float v = __expf(f - fm);
    bool sel = u > te;
    unsigned long long mask = __ballot(sel);
    int nsel = __popcll(mask);
    int base = 0;
    if (lane == 0 && nsel) base = atomicAdd(&cnt[e], nsel);
    base = __shfl(base, 0, 64);
    if (sel) {
      int slot = base + __popcll(mask & ((1ull << lane) - 1ull));
      idxo[e * CAP + slot] = t;
      exo[e * CAP + slot] = v;
    }
    float vs = sel ? v : 0.f;
#pragma unroll
    for (int off = 32; off > 0; off >>= 1) vs += __shfl_xor(vs, off, 64);
    if (lane == 0 && vs != 0.f) atomicAdd(&expsum[e], vs);
    // rare tie path (== threshold): admit exactly need[e]
    if (u == te) {
      int k = atomicAdd(&tie[e], 1);
      if (k < need[e]) {
        int slot = atomicAdd(&cnt[e], 1);
        idxo[e * CAP + slot] = t;
        exo[e * CAP + slot] = v;
        atomicAdd(&expsum[e], v);
      }
    }
  }
}

// ------------------------------ fused weight transpose + cast (w1, w3, w2)
// in: [E][R][C] fp32  ->  out: [E][C][R] bf16
__global__ void __launch_bounds__(256) transpose3_k(
    const float* __restrict__ w1, const float* __restrict__ w3, const float* __restrict__ w2,
    ushort_t* __restrict__ w1t, ushort_t* __restrict__ w3t, ushort_t* __restrict__ w2t)
{
  __shared__ float tile[64][65];
  int b = blockIdx.x;
  const float* in; ushort_t* out; int R, Cc;
  if (b < 4096)      { in = w1; out = w1t; R = HDIM; Cc = FDIM; }
  else if (b < 8192) { in = w3; out = w3t; R = HDIM; Cc = FDIM; b -= 4096; }
  else               { in = w2; out = w2t; R = FDIM; Cc = HDIM; b -= 8192; }
  int tilesC = Cc >> 6;
  int tilesPer = (R >> 6) * tilesC;
  int e = b / tilesPer;
  int tb = b - e * tilesPer;
  int rt = tb / tilesC, ct = tb - rt * tilesC;
  const float* src = in + (size_t)e * R * Cc;
  ushort_t* dst = out + (size_t)e * R * Cc;
  int tr = threadIdx.x >> 4, tc = threadIdx.x & 15;
#pragma unroll
  for (int it = 0; it < 4; ++it) {
    int r = (rt << 6) + (it << 4) + tr;
    int c = (ct << 6) + (tc << 2);
    float4 v = *(const float4*)(src + (size_t)r * Cc + c);
    tile[(it << 4) + tr][(tc << 2) + 0] = v.x;
    tile[(it << 4) + tr][(tc << 2) + 1] = v.y;
    tile[(it << 4) + tr][(tc << 2) + 2] = v.z;
    tile[(it << 4) + tr][(tc << 2) + 3] = v.w;
  }
  __syncthreads();
#pragma unroll
  for (int it = 0; it < 4; ++it) {
    int cl = (it << 4) + tr;
    int rl = tc << 2;
    unsigned lo = pk2(f2b(tile[rl + 0][cl]), f2b(tile[rl + 1][cl]));
    unsigned hi = pk2(f2b(tile[rl + 2][cl]), f2b(tile[rl + 3][cl]));
    unsigned long long v = (unsigned long long)lo | ((unsigned long long)hi << 32);
    *(unsigned long long*)(dst + (size_t)((ct << 6) + cl) * R + (rt << 6) + rl) = v;
  }
}

// ------------------------------------------------- GEMM1: SwiGLU hidden (bf16 MFMA)
// 128x64 tile, dual accumulator (X.W1, X.W3), fused SiLU*mul. 64 AGPR/wave.
__global__ void __launch_bounds__(256) gemm1_swiglu_k(
    const ushort_t* __restrict__ xb,   // [T_TOK][HDIM]
    const ushort_t* __restrict__ w1t,  // [E][FDIM][HDIM]
    const ushort_t* __restrict__ w3t,
    const int* __restrict__ idx,       // [E][CAP]
    ushort_t* __restrict__ hidden)     // [E][CAP][FDIM]
{
  int b = blockIdx.x;
  int ni_ = b & 7; int t1 = b >> 3; int mt = t1 % 10; int t2 = t1 / 10;
  int ng = t2 & 3; int e = t2 >> 2;
  int nt = ng * 8 + ni_;             // 0..31

  __shared__ __bf16 Alds[128 * 32];
  __shared__ __bf16 B1lds[64 * 32];
  __shared__ __bf16 B3lds[64 * 32];

  int tid = threadIdx.x;
  int lane = tid & 63, wave = tid >> 6;
  int wm = wave & 1, wn = wave >> 1;
  int l15 = lane & 15, quad = lane >> 4;

  int r0 = tid >> 2, kc0 = tid & 3;
  int r1 = r0 + 64;
  const int* idxe = idx + e * CAP + mt * 128;
  const ushort_t* a0 = xb + (size_t)idxe[r0] * HDIM + kc0 * 8;
  const ushort_t* a1 = xb + (size_t)idxe[r1] * HDIM + kc0 * 8;
  const ushort_t* wb1 = w1t + ((size_t)e * FDIM + nt * 64) * HDIM;
  const ushort_t* wb3 = w3t + ((size_t)e * FDIM + nt * 64) * HDIM;
  const ushort_t* b1p = wb1 + (size_t)r0 * HDIM + kc0 * 8;
  const ushort_t* b3p = wb3 + (size_t)r0 * HDIM + kc0 * 8;

  f32x4 acc1[4][2];
  f32x4 acc3[4][2];
#pragma unroll
  for (int i = 0; i < 4; ++i)
#pragma unroll
    for (int j = 0; j < 2; ++j) {
      acc1[i][j] = (f32x4){0.f, 0.f, 0.f, 0.f};
      acc3[i][j] = (f32x4){0.f, 0.f, 0.f, 0.f};
    }

  for (int kt = 0; kt < HDIM / 32; ++kt) {
    gl_lds16(a0,  Alds  + (size_t)tid * 8);
    gl_lds16(a1,  Alds  + (size_t)(tid + 256) * 8);
    gl_lds16(b1p, B1lds + (size_t)tid * 8);
    gl_lds16(b3p, B3lds + (size_t)tid * 8);
    __syncthreads();

    bf16x8 af[4], bf1[2], bf3[2];
#pragma unroll
    for (int i = 0; i < 4; ++i)
      af[i]  = *(const bf16x8*)(Alds  + ((wm * 64 + i * 16 + l15) * 32 + quad * 8));
#pragma unroll
    for (int j = 0; j < 2; ++j) {
      bf1[j] = *(const bf16x8*)(B1lds + ((wn * 32 + j * 16 + l15) * 32 + quad * 8));
      bf3[j] = *(const bf16x8*)(B3lds + ((wn * 32 + j * 16 + l15) * 32 + quad * 8));
    }
#pragma unroll
    for (int mi = 0; mi < 4; ++mi)
#pragma unroll
      for (int nj = 0; nj < 2; ++nj) {
        acc1[mi][nj] = __builtin_amdgcn_mfma_f32_16x16x32_bf16(af[mi], bf1[nj], acc1[mi][nj], 0, 0, 0);
        acc3[mi][nj] = __builtin_amdgcn_mfma_f32_16x16x32_bf16(af[mi], bf3[nj], acc3[mi][nj], 0, 0, 0);
      }
    __syncthreads();
    a0 += 32; a1 += 32; b1p += 32; b3p += 32;
  }

  // C/D layout: col = lane&15, row = quad*4 + reg  [verified m89/m91]
  ushort_t* hb = hidden + ((size_t)e * CAP + mt * 128) * FDIM + nt * 64;
#pragma unroll
  for (int mi = 0; mi < 4; ++mi)
#pragma unroll
    for (int nj = 0; nj < 2; ++nj)
#pragma unroll
      for (int r = 0; r < 4; ++r) {
        int row = wm * 64 + mi * 16 + quad * 4 + r;
        int col = wn * 32 + nj * 16 + l15;
        float v1 = acc1[mi][nj][r];
        float v3 = acc3[mi][nj][r];
        float s = (v1 / (1.f + __expf(-v1))) * v3;
        hb[(size_t)row * FDIM + col] = f2b(s);
      }
}

// ------------------------------------- GEMM2: hidden @ w2 -> weighted scatter-add
// split-K = 2; weight = ex[row] / expsum[e] (order-free softmax normalization)
__global__ void __launch_bounds__(256) gemm2_scatter_k(
    const ushort_t* __restrict__ hidden, // [E][CAP][FDIM]
    const ushort_t* __restrict__ w2t,    // [E][HDIM][FDIM]
    const int* __restrict__ idx,
    const float* __restrict__ ex, const float* __restrict__ expsum,
    float* __restrict__ y)               // [T_TOK][HDIM]
{
  int b = blockIdx.x;
  int nt = b & 7; int t1 = b >> 3; int mt = t1 % 10; int t2 = t1 / 10;
  int kk = t2 & 1; int e = t2 >> 1;

  __shared__ __bf16 Alds[128 * 32];
  __shared__ __bf16 Blds[128 * 32];
  __shared__ int   idxs[128];
  __shared__ float wgts[128];

  int tid = threadIdx.x;
  int lane = tid & 63, wave = tid >> 6;
  int wm = wave & 1, wn = wave >> 1;
  int l15 = lane & 15, quad = lane >> 4;

  if (tid < 128) {
    idxs[tid] = idx[e * CAP + mt * 128 + tid];
    wgts[tid] = ex[e * CAP + mt * 128 + tid] / expsum[e];
  }

  int r0 = tid >> 2, kc0 = tid & 3;
  int r1 = r0 + 64;
  size_t kof = (size_t)kk * (FDIM / 2);
  const ushort_t* a0 = hidden + ((size_t)e * CAP + mt * 128 + r0) * FDIM + kof + kc0 * 8;
  const ushort_t* a1 = hidden + ((size_t)e * CAP + mt * 128 + r1) * FDIM + kof + kc0 * 8;
  const ushort_t* b0 = w2t + ((size_t)e * HDIM + nt * 128 + r0) * FDIM + kof + kc0 * 8;
  const ushort_t* b1 = w2t + ((size_t)e * HDIM + nt * 128 + r1) * FDIM + kof + kc0 * 8;

  f32x4 acc[4][4];
#pragma unroll
  for (int i = 0; i < 4; ++i)
#pragma unroll
    for (int j = 0; j < 4; ++j) acc[i][j] = (f32x4){0.f, 0.f, 0.f, 0.f};

  for (int kt = 0; kt < (FDIM / 2) / 32; ++kt) {
    gl_lds16(a0, Alds + (size_t)tid * 8);
    gl_lds16(a1, Alds + (size_t)(tid + 256) * 8);
    gl_lds16(b0, Blds + (size_t)tid * 8);
    gl_lds16(b1, Blds + (size_t)(tid + 256) * 8);
    __syncthreads();

    bf16x8 af[4], bf[4];
#pragma unroll
    for (int i = 0; i < 4; ++i) {
      af[i] = *(const bf16x8*)(Alds + ((wm * 64 + i * 16 + l15) * 32 + quad * 8));
      bf[i] = *(const bf16x8*)(Blds + ((wn * 64 + i * 16 + l15) * 32 + quad * 8));
    }
#pragma unroll
    for (int mi = 0; mi < 4; ++mi)
#pragma unroll
      for (int nj = 0; nj < 4; ++nj)
        acc[mi][nj] = __builtin_amdgcn_mfma_f32_16x16x32_bf16(af[mi], bf[nj], acc[mi][nj], 0, 0, 0);
    __syncthreads();
    a0 += 32; a1 += 32; b0 += 32; b1 += 32;
  }

#pragma unroll
  for (int mi = 0; mi < 4; ++mi)
#pragma unroll
    for (int nj = 0; nj < 4; ++nj)
#pragma unroll
      for (int r = 0; r < 4; ++r) {
        int row = wm * 64 + mi * 16 + quad * 4 + r;
        int col = nt * 128 + wn * 64 + nj * 16 + l15;
        float v = acc[mi][nj][r] * wgts[row];
        atomicAdd(y + (size_t)idxs[row] * HDIM + col, v);
      }
}

// --------------------------------------------------------------------- launch
extern "C" void kernel_launch(void* const* d_in, const int* in_sizes, int n_in,
                              void* d_out, int out_size, void* d_ws, size_t ws_size,
                              hipStream_t stream)
{
  const float* x  = (const float*)d_in[0];
  const float* gw = (const float*)d_in[1];
  const float* w1 = (const float*)d_in[2];
  const float* w2 = (const float*)d_in[3];
  const float* w3 = (const float*)d_in[4];
  float* y = (float*)d_out;

  char* ws = (char*)d_ws;
  float*    logitsT = (float*)(ws + 0x0);          // 256 KB [E][T]
  int*      idx     = (int*)(ws + 0x40000);        // 40 KB
  float*    exo     = (float*)(ws + 0x4A000);      // 40 KB (raw exp values)
  // control block at 0x54000 (zeroed each launch): thr,need,umax,cnt,tie,expsum
  unsigned* thr    = (unsigned*)(ws + 0x54000);
  int*      need   = (int*)(ws + 0x54020);
  unsigned* umax   = (unsigned*)(ws + 0x54040);
  int*      cnt    = (int*)(ws + 0x54060);
  int*      tie    = (int*)(ws + 0x54080);
  float*    expsum = (float*)(ws + 0x540A0);
  ushort_t* xb     = (ushort_t*)(ws + 0x60000);    // 16 MB  [T][H] bf16
  ushort_t* w1t    = (ushort_t*)(ws + 0x1060000);  // 32 MB  [E][F][H]
  ushort_t* w3t    = (ushort_t*)(ws + 0x3060000);  // 32 MB
  ushort_t* w2t    = (ushort_t*)(ws + 0x5060000);  // 32 MB  [E][H][F]
  ushort_t* hid    = (ushort_t*)(ws + 0x7060000);  // 40 MB  [E][CAP][F]

  hipMemsetAsync(d_out, 0, (size_t)out_size * sizeof(float), stream);
  hipMemsetAsync(ws + 0x54000, 0, 256, stream);
  gate_cast_k<<<T_TOK / 4, 256, 0, stream>>>(x, gw, logitsT, xb);
  select_k<<<EXP, 256, 0, stream>>>(logitsT, thr, need, umax);
  emit_k<<<T_TOK / 256, 256, 0, stream>>>(logitsT, thr, need, umax, idx, exo, cnt, tie, expsum);
  transpose3_k<<<3 * 4096, 256, 0, stream>>>(w1, w3, w2, w1t, w3t, w2t);
  gemm1_swiglu_k<<<EXP * 4 * 10 * 8, 256, 0, stream>>>(xb, w1t, w3t, idx, hid);
  gemm2_scatter_k<<<EXP * 2 * 10 * 8, 256, 0, stream>>>(hid, w2t, idx, exo, expsum, y);
}

// Round 4
// 489.233 us; speedup vs baseline: 1.2363x; 1.2363x over previous
//
#include <hip/hip_runtime.h>
#include <stdint.h>

typedef unsigned short ushort_t;
typedef __bf16 bf16x8 __attribute__((ext_vector_type(8)));
typedef float f32x4 __attribute__((ext_vector_type(4)));

#define T_TOK 8192
#define HDIM  1024
#define EXP   8
#define FDIM  2048
#define CAP   1280

// fp32 -> bf16 round-to-nearest-even
__device__ __forceinline__ unsigned short f2b(float f) {
  unsigned u = __float_as_uint(f);
  u = (u + 0x7fffu + ((u >> 16) & 1u)) >> 16;
  return (unsigned short)u;
}
__device__ __forceinline__ unsigned pk2(unsigned short lo, unsigned short hi) {
  return (unsigned)lo | ((unsigned)hi << 16);
}
// order-preserving fp32 -> u32 map (monotone increasing)
__device__ __forceinline__ unsigned map_u(float f) {
  unsigned u = __float_as_uint(f);
  return (u & 0x80000000u) ? ~u : (u | 0x80000000u);
}
__device__ __forceinline__ float unmap_f(unsigned m) {
  unsigned u = (m & 0x80000000u) ? (m ^ 0x80000000u) : ~m;
  return __uint_as_float(u);
}
// async global->LDS, 16B/lane; LDS dest = wave-uniform base + lane*16
__device__ __forceinline__ void gl_lds16(const void* g, void* l) {
  __builtin_amdgcn_global_load_lds((__attribute__((address_space(1))) void*)g,
                                   (__attribute__((address_space(3))) void*)l,
                                   16, 0, 0);
}

// ------------------------------------------- gating GEMV + x->bf16 cast (fused)
__global__ void __launch_bounds__(256) gate_cast_k(
    const float* __restrict__ x, const float* __restrict__ gw,
    float* __restrict__ logitsT, ushort_t* __restrict__ xb)
{
  int wave = threadIdx.x >> 6, lane = threadIdx.x & 63;
  int t = blockIdx.x * 4 + wave;
  const float* xr = x + (size_t)t * HDIM;
  ushort_t* xbr = xb + (size_t)t * HDIM;
  float acc[8];
#pragma unroll
  for (int i = 0; i < 8; ++i) acc[i] = 0.f;
#pragma unroll
  for (int i = 0; i < 16; ++i) {
    int h = i * 64 + lane;
    float xv = xr[h];
    xbr[h] = f2b(xv);
    const float4* g4 = (const float4*)(gw + (size_t)h * EXP);
    float4 lo = g4[0], hi = g4[1];
    acc[0] += xv * lo.x; acc[1] += xv * lo.y; acc[2] += xv * lo.z; acc[3] += xv * lo.w;
    acc[4] += xv * hi.x; acc[5] += xv * hi.y; acc[6] += xv * hi.z; acc[7] += xv * hi.w;
  }
#pragma unroll
  for (int off = 32; off > 0; off >>= 1) {
#pragma unroll
    for (int i = 0; i < 8; ++i) acc[i] += __shfl_xor(acc[i], off, 64);
  }
  if (lane == 0) {
#pragma unroll
    for (int i = 0; i < 8; ++i) logitsT[(size_t)i * T_TOK + t] = acc[i];
  }
}

// ------------------------------- radix-select: exact CAP-th largest per expert
// parallel suffix-scan replaces serial bin walk; shuffle-reduce max.
__global__ void __launch_bounds__(256) select_k(
    const float* __restrict__ logitsT,
    unsigned* __restrict__ thr, int* __restrict__ needo, unsigned* __restrict__ umax)
{
  __shared__ int hist[256];
  __shared__ int ssum[256];
  __shared__ unsigned s_pref;
  __shared__ int s_rem;
  __shared__ unsigned smx[4];
  int e = blockIdx.x, tid = threadIdx.x;
  const float* base = logitsT + (size_t)e * T_TOK;

  unsigned m[32];
  unsigned mmax = 0;
#pragma unroll
  for (int i = 0; i < 32; ++i) {
    m[i] = map_u(base[tid + i * 256]);
    mmax = m[i] > mmax ? m[i] : mmax;
  }
#pragma unroll
  for (int off = 32; off > 0; off >>= 1) {
    unsigned o = __shfl_xor(mmax, off, 64);
    mmax = o > mmax ? o : mmax;
  }
  int lane = tid & 63, wv = tid >> 6;
  if (lane == 0) smx[wv] = mmax;
  if (tid == 0) { s_pref = 0; s_rem = CAP; }
  __syncthreads();
  if (tid == 0) {
    unsigned a = smx[0] > smx[1] ? smx[0] : smx[1];
    unsigned b = smx[2] > smx[3] ? smx[2] : smx[3];
    umax[e] = a > b ? a : b;
  }

  for (int r = 0; r < 4; ++r) {
    hist[tid] = 0;
    __syncthreads();
    unsigned pref = s_pref;
    int rem = s_rem;
    int shift = 24 - 8 * r;
#pragma unroll
    for (int i = 0; i < 32; ++i) {
      unsigned u = m[i];
      bool ok = (r == 0) || ((u >> (shift + 8)) == (pref >> (shift + 8)));
      if (ok) atomicAdd(&hist[(u >> shift) & 255], 1);
    }
    __syncthreads();
    ssum[tid] = hist[tid];
    __syncthreads();
    for (int st = 1; st < 256; st <<= 1) {
      int add = (tid + st < 256) ? ssum[tid + st] : 0;
      __syncthreads();
      ssum[tid] += add;
      __syncthreads();
    }
    int above = (tid < 255) ? ssum[tid + 1] : 0;   // count strictly above bin tid
    if (ssum[tid] >= rem && above < rem) {
      s_pref = pref | ((unsigned)tid << shift);
      s_rem = rem - above;
    }
    __syncthreads();
  }
  if (tid == 0) { thr[e] = s_pref; needo[e] = s_rem; }
}

// ------------------------- emit: threshold test + slot assign + token lists
__global__ void __launch_bounds__(256) emit_k(
    const float* __restrict__ logitsT,
    const unsigned* __restrict__ thr, const int* __restrict__ needv,
    const unsigned* __restrict__ umaxv,
    int* __restrict__ idxo, float* __restrict__ exo,
    int* __restrict__ cnt, int* __restrict__ tie, float* __restrict__ expsum,
    int* __restrict__ tok_cnt, int* __restrict__ tok_ent)
{
  int t = blockIdx.x * 256 + threadIdx.x;
  int lane = threadIdx.x & 63;
  int lc = 0;
  int ents[8];
#pragma unroll
  for (int e = 0; e < EXP; ++e) {
    float f = logitsT[(size_t)e * T_TOK + t];
    unsigned u = map_u(f);
    unsigned te = thr[e];
    float fm = unmap_f(umaxv[e]);
    float v = __expf(f - fm);
    bool sel = u > te;
    unsigned long long mask = __ballot(sel);
    int nsel = __popcll(mask);
    int base = 0;
    if (lane == 0 && nsel) base = atomicAdd(&cnt[e], nsel);
    base = __shfl(base, 0, 64);
    int slot = -1;
    if (sel) slot = base + __popcll(mask & ((1ull << lane) - 1ull));
    // rare tie path (== threshold): admit exactly needv[e]
    if (u == te) {
      int k = atomicAdd(&tie[e], 1);
      if (k < needv[e]) {
        slot = atomicAdd(&cnt[e], 1);
        atomicAdd(&expsum[e], v);
      }
    }
    if (slot >= 0) {
      idxo[e * CAP + slot] = t;
      exo[e * CAP + slot] = v;
      ents[lc++] = (e << 16) | slot;
    }
    float vs = sel ? v : 0.f;
#pragma unroll
    for (int off = 32; off > 0; off >>= 1) vs += __shfl_xor(vs, off, 64);
    if (lane == 0 && vs != 0.f) atomicAdd(&expsum[e], vs);
  }
  tok_cnt[t] = lc;
  for (int i = 0; i < lc; ++i) tok_ent[t * 8 + i] = ents[i];
}

// ------------------------------ fused weight transpose + cast (w1, w3, w2)
__global__ void __launch_bounds__(256) transpose3_k(
    const float* __restrict__ w1, const float* __restrict__ w3, const float* __restrict__ w2,
    ushort_t* __restrict__ w1t, ushort_t* __restrict__ w3t, ushort_t* __restrict__ w2t)
{
  __shared__ float tile[64][65];
  int b = blockIdx.x;
  const float* in; ushort_t* out; int R, Cc;
  if (b < 4096)      { in = w1; out = w1t; R = HDIM; Cc = FDIM; }
  else if (b < 8192) { in = w3; out = w3t; R = HDIM; Cc = FDIM; b -= 4096; }
  else               { in = w2; out = w2t; R = FDIM; Cc = HDIM; b -= 8192; }
  int tilesC = Cc >> 6;
  int tilesPer = (R >> 6) * tilesC;
  int e = b / tilesPer;
  int tb = b - e * tilesPer;
  int rt = tb / tilesC, ct = tb - rt * tilesC;
  const float* src = in + (size_t)e * R * Cc;
  ushort_t* dst = out + (size_t)e * R * Cc;
  int tr = threadIdx.x >> 4, tc = threadIdx.x & 15;
#pragma unroll
  for (int it = 0; it < 4; ++it) {
    int r = (rt << 6) + (it << 4) + tr;
    int c = (ct << 6) + (tc << 2);
    float4 v = *(const float4*)(src + (size_t)r * Cc + c);
    tile[(it << 4) + tr][(tc << 2) + 0] = v.x;
    tile[(it << 4) + tr][(tc << 2) + 1] = v.y;
    tile[(it << 4) + tr][(tc << 2) + 2] = v.z;
    tile[(it << 4) + tr][(tc << 2) + 3] = v.w;
  }
  __syncthreads();
#pragma unroll
  for (int it = 0; it < 4; ++it) {
    int cl = (it << 4) + tr;
    int rl = tc << 2;
    unsigned lo = pk2(f2b(tile[rl + 0][cl]), f2b(tile[rl + 1][cl]));
    unsigned hi = pk2(f2b(tile[rl + 2][cl]), f2b(tile[rl + 3][cl]));
    unsigned long long v = (unsigned long long)lo | ((unsigned long long)hi << 32);
    *(unsigned long long*)(dst + (size_t)((ct << 6) + cl) * R + (rt << 6) + rl) = v;
  }
}

// ------------------------------------------------- GEMM1: SwiGLU hidden (bf16 MFMA)
// 128x64 tile, BK=64, XOR-swizzled LDS (kc ^= row&7) -> conflict-free ds_read_b128.
__global__ void __launch_bounds__(256) gemm1_swiglu_k(
    const ushort_t* __restrict__ xb,   // [T_TOK][HDIM]
    const ushort_t* __restrict__ w1t,  // [E][FDIM][HDIM]
    const ushort_t* __restrict__ w3t,
    const int* __restrict__ idx,       // [E][CAP]
    ushort_t* __restrict__ hidden)     // [E][CAP][FDIM]
{
  int b = blockIdx.x;
  int ni_ = b & 7; int t1 = b >> 3; int mt = t1 % 10; int t2 = t1 / 10;
  int ng = t2 & 3; int e = t2 >> 2;
  int nt = ng * 8 + ni_;             // 0..31

  __shared__ __bf16 Alds[128 * 64];  // 16 KB
  __shared__ __bf16 B1lds[64 * 64];  // 8 KB
  __shared__ __bf16 B3lds[64 * 64];  // 8 KB

  int tid = threadIdx.x;
  int lane = tid & 63, wave = tid >> 6;
  int wm = wave & 1, wn = wave >> 1;
  int l15 = lane & 15, quad = lane >> 4;

  int kc = tid & 7;                  // 16B chunk within a 128B row
  int r0 = tid >> 3;                 // 0..31
  const int* idxe = idx + e * CAP + mt * 128;
  const ushort_t* a_ptr[4];
#pragma unroll
  for (int j = 0; j < 4; ++j) {
    int row = r0 + j * 32;
    a_ptr[j] = xb + (size_t)idxe[row] * HDIM + ((kc ^ (row & 7)) * 8);
  }
  const ushort_t* wb1 = w1t + ((size_t)e * FDIM + nt * 64) * HDIM;
  const ushort_t* wb3 = w3t + ((size_t)e * FDIM + nt * 64) * HDIM;
  const ushort_t* b1_ptr[2];
  const ushort_t* b3_ptr[2];
#pragma unroll
  for (int j = 0; j < 2; ++j) {
    int row = r0 + j * 32;
    size_t off = (size_t)row * HDIM + ((kc ^ (row & 7)) * 8);
    b1_ptr[j] = wb1 + off;
    b3_ptr[j] = wb3 + off;
  }

  f32x4 acc1[4][2], acc3[4][2];
#pragma unroll
  for (int i = 0; i < 4; ++i)
#pragma unroll
    for (int j = 0; j < 2; ++j) {
      acc1[i][j] = (f32x4){0.f, 0.f, 0.f, 0.f};
      acc3[i][j] = (f32x4){0.f, 0.f, 0.f, 0.f};
    }

  for (int kt = 0; kt < HDIM / 64; ++kt) {
#pragma unroll
    for (int j = 0; j < 4; ++j) gl_lds16(a_ptr[j], Alds + ((size_t)tid + j * 256) * 8);
#pragma unroll
    for (int j = 0; j < 2; ++j) {
      gl_lds16(b1_ptr[j], B1lds + ((size_t)tid + j * 256) * 8);
      gl_lds16(b3_ptr[j], B3lds + ((size_t)tid + j * 256) * 8);
    }
    __syncthreads();
#pragma unroll
    for (int kh = 0; kh < 2; ++kh) {
      bf16x8 af[4], bf1[2], bf3[2];
#pragma unroll
      for (int i = 0; i < 4; ++i) {
        int row = wm * 64 + i * 16 + l15;
        af[i] = *(const bf16x8*)(Alds + row * 64 + (((kh * 4 + quad) ^ (row & 7)) * 8));
      }
#pragma unroll
      for (int j = 0; j < 2; ++j) {
        int row = wn * 32 + j * 16 + l15;
        int o = row * 64 + (((kh * 4 + quad) ^ (row & 7)) * 8);
        bf1[j] = *(const bf16x8*)(B1lds + o);
        bf3[j] = *(const bf16x8*)(B3lds + o);
      }
#pragma unroll
      for (int mi = 0; mi < 4; ++mi)
#pragma unroll
        for (int nj = 0; nj < 2; ++nj) {
          acc1[mi][nj] = __builtin_amdgcn_mfma_f32_16x16x32_bf16(af[mi], bf1[nj], acc1[mi][nj], 0, 0, 0);
          acc3[mi][nj] = __builtin_amdgcn_mfma_f32_16x16x32_bf16(af[mi], bf3[nj], acc3[mi][nj], 0, 0, 0);
        }
    }
    __syncthreads();
#pragma unroll
    for (int j = 0; j < 4; ++j) a_ptr[j] += 64;
#pragma unroll
    for (int j = 0; j < 2; ++j) { b1_ptr[j] += 64; b3_ptr[j] += 64; }
  }

  // C/D layout: col = lane&15, row = quad*4 + reg  [verified m89/m91]
  ushort_t* hb = hidden + ((size_t)e * CAP + mt * 128) * FDIM + nt * 64;
#pragma unroll
  for (int mi = 0; mi < 4; ++mi)
#pragma unroll
    for (int nj = 0; nj < 2; ++nj)
#pragma unroll
      for (int r = 0; r < 4; ++r) {
        int row = wm * 64 + mi * 16 + quad * 4 + r;
        int col = wn * 32 + nj * 16 + l15;
        float v1 = acc1[mi][nj][r];
        float v3 = acc3[mi][nj][r];
        float s = (v1 / (1.f + __expf(-v1))) * v3;
        hb[(size_t)row * FDIM + col] = f2b(s);
      }
}

// ------------------------------------- GEMM2: hidden @ w2 -> weighted store (no atomics)
__global__ void __launch_bounds__(256) gemm2_k(
    const ushort_t* __restrict__ hidden, // [E][CAP][FDIM]
    const ushort_t* __restrict__ w2t,    // [E][HDIM][FDIM]
    const float* __restrict__ ex, const float* __restrict__ expsum,
    float* __restrict__ oute)            // [E][CAP][HDIM] fp32, weighted
{
  // b = (e*10 + mt)*8 + nt
  int b = blockIdx.x;
  int nt = b & 7; int t1 = b >> 3; int mt = t1 % 10; int e = t1 / 10;

  __shared__ __bf16 Alds[128 * 64];  // 16 KB
  __shared__ __bf16 Blds[128 * 64];  // 16 KB
  __shared__ float wgts[128];

  int tid = threadIdx.x;
  int lane = tid & 63, wave = tid >> 6;
  int wm = wave & 1, wn = wave >> 1;
  int l15 = lane & 15, quad = lane >> 4;

  if (tid < 128) wgts[tid] = ex[e * CAP + mt * 128 + tid] / expsum[e];

  int kc = tid & 7;
  int r0 = tid >> 3;
  const ushort_t* a_ptr[4];
  const ushort_t* b_ptr[4];
#pragma unroll
  for (int j = 0; j < 4; ++j) {
    int row = r0 + j * 32;
    a_ptr[j] = hidden + ((size_t)e * CAP + mt * 128 + row) * FDIM + ((kc ^ (row & 7)) * 8);
    b_ptr[j] = w2t + ((size_t)e * HDIM + nt * 128 + row) * FDIM + ((kc ^ (row & 7)) * 8);
  }

  f32x4 acc[4][4];
#pragma unroll
  for (int i = 0; i < 4; ++i)
#pragma unroll
    for (int j = 0; j < 4; ++j) acc[i][j] = (f32x4){0.f, 0.f, 0.f, 0.f};

  for (int kt = 0; kt < FDIM / 64; ++kt) {
#pragma unroll
    for (int j = 0; j < 4; ++j) {
      gl_lds16(a_ptr[j], Alds + ((size_t)tid + j * 256) * 8);
      gl_lds16(b_ptr[j], Blds + ((size_t)tid + j * 256) * 8);
    }
    __syncthreads();
#pragma unroll
    for (int kh = 0; kh < 2; ++kh) {
      bf16x8 af[4], bf[4];
#pragma unroll
      for (int i = 0; i < 4; ++i) {
        int rowa = wm * 64 + i * 16 + l15;
        af[i] = *(const bf16x8*)(Alds + rowa * 64 + (((kh * 4 + quad) ^ (rowa & 7)) * 8));
        int rowb = wn * 64 + i * 16 + l15;
        bf[i] = *(const bf16x8*)(Blds + rowb * 64 + (((kh * 4 + quad) ^ (rowb & 7)) * 8));
      }
#pragma unroll
      for (int mi = 0; mi < 4; ++mi)
#pragma unroll
        for (int nj = 0; nj < 4; ++nj)
          acc[mi][nj] = __builtin_amdgcn_mfma_f32_16x16x32_bf16(af[mi], bf[nj], acc[mi][nj], 0, 0, 0);
    }
    __syncthreads();
#pragma unroll
    for (int j = 0; j < 4; ++j) { a_ptr[j] += 64; b_ptr[j] += 64; }
  }

  float* ob = oute + ((size_t)e * CAP + mt * 128) * HDIM + nt * 128;
#pragma unroll
  for (int mi = 0; mi < 4; ++mi)
#pragma unroll
    for (int nj = 0; nj < 4; ++nj)
#pragma unroll
      for (int r = 0; r < 4; ++r) {
        int row = wm * 64 + mi * 16 + quad * 4 + r;
        int col = wn * 64 + nj * 16 + l15;
        ob[(size_t)row * HDIM + col] = acc[mi][nj][r] * wgts[row];
      }
}

// ---------------------------------------- combine: per-token gather-sum -> y
__global__ void __launch_bounds__(256) combine_k(
    const float* __restrict__ oute,      // [E][CAP][HDIM] weighted
    const int* __restrict__ tok_cnt, const int* __restrict__ tok_ent,
    float* __restrict__ y)               // [T_TOK][HDIM]
{
  int t = blockIdx.x;
  int c = threadIdx.x * 4;
  int n = tok_cnt[t];
  float4 acc = {0.f, 0.f, 0.f, 0.f};
  for (int i = 0; i < n; ++i) {
    int ent = tok_ent[t * 8 + i];
    int e = ent >> 16, slot = ent & 0xffff;
    float4 v = *(const float4*)(oute + (((size_t)e * CAP + slot) << 10) + c);
    acc.x += v.x; acc.y += v.y; acc.z += v.z; acc.w += v.w;
  }
  *(float4*)(y + ((size_t)t << 10) + c) = acc;
}

// --------------------------------------------------------------------- launch
extern "C" void kernel_launch(void* const* d_in, const int* in_sizes, int n_in,
                              void* d_out, int out_size, void* d_ws, size_t ws_size,
                              hipStream_t stream)
{
  const float* x  = (const float*)d_in[0];
  const float* gw = (const float*)d_in[1];
  const float* w1 = (const float*)d_in[2];
  const float* w2 = (const float*)d_in[3];
  const float* w3 = (const float*)d_in[4];
  float* y = (float*)d_out;

  char* ws = (char*)d_ws;
  float*    logitsT = (float*)(ws + 0x0);          // 256 KB [E][T]
  int*      idx     = (int*)(ws + 0x40000);        // 40 KB
  float*    exo     = (float*)(ws + 0x4A000);      // 40 KB
  unsigned* thr    = (unsigned*)(ws + 0x54000);    // ctrl block (zeroed): 256 B
  int*      need   = (int*)(ws + 0x54020);
  unsigned* umax   = (unsigned*)(ws + 0x54040);
  int*      cnt    = (int*)(ws + 0x54060);
  int*      tie    = (int*)(ws + 0x54080);
  float*    expsum = (float*)(ws + 0x540A0);
  int*      tok_cnt = (int*)(ws + 0x55000);        // 32 KB
  int*      tok_ent = (int*)(ws + 0x5D000);        // 256 KB
  ushort_t* xb     = (ushort_t*)(ws + 0xA0000);    // 16 MB  [T][H] bf16
  ushort_t* w1t    = (ushort_t*)(ws + 0x10A0000);  // 32 MB  [E][F][H]
  ushort_t* w3t    = (ushort_t*)(ws + 0x30A0000);  // 32 MB
  ushort_t* w2t    = (ushort_t*)(ws + 0x50A0000);  // 32 MB  [E][H][F]
  ushort_t* hid    = (ushort_t*)(ws + 0x70A0000);  // 40 MB  [E][CAP][F]
  float*    oute   = (float*)(ws + 0x10A0000);     // 40 MB, aliases w1t+w3t (dead after gemm1)

  // tail of d_out beyond y (the scalar 0.0 output) must be zero
  size_t yelems = (size_t)T_TOK * HDIM;
  if ((size_t)out_size > yelems)
    hipMemsetAsync((char*)d_out + yelems * 4, 0, ((size_t)out_size - yelems) * 4, stream);
  hipMemsetAsync(ws + 0x54000, 0, 256, stream);

  transpose3_k<<<3 * 4096, 256, 0, stream>>>(w1, w3, w2, w1t, w3t, w2t);
  gate_cast_k<<<T_TOK / 4, 256, 0, stream>>>(x, gw, logitsT, xb);
  select_k<<<EXP, 256, 0, stream>>>(logitsT, thr, need, umax);
  emit_k<<<T_TOK / 256, 256, 0, stream>>>(logitsT, thr, need, umax, idx, exo, cnt, tie, expsum, tok_cnt, tok_ent);
  gemm1_swiglu_k<<<EXP * 4 * 10 * 8, 256, 0, stream>>>(xb, w1t, w3t, idx, hid);
  gemm2_k<<<EXP * 10 * 8, 256, 0, stream>>>(hid, w2t, exo, expsum, oute);
  combine_k<<<T_TOK, 256, 0, stream>>>(oute, tok_cnt, tok_ent, y);
}